// Round 5
// baseline (831.524 us; speedup 1.0000x reference)
//
#include <hip/hip_runtime.h>
#include <stdint.h>

#define M_ROWS 8192
#define K_DIM  4096
#define N_DIM  11008
#define KSTEPS (K_DIM / 64)      // 64 K-tiles of BK=64

// ---- 256x256 8-phase geometry ----
#define BM 256
#define BN 256
#define MBLKS (M_ROWS / BM)      // 32
#define NBLKS (N_DIM / BN)       // 43
#define NWG   (MBLKS * NBLKS)    // 1376 = 8 XCDs x 172 slots

typedef __attribute__((ext_vector_type(4))) float          f32x4;
typedef __attribute__((ext_vector_type(8))) __bf16         bf16x8;
typedef __attribute__((ext_vector_type(4))) int            i32x4;
typedef __attribute__((ext_vector_type(8))) unsigned short u16x8;

__constant__ float NF4_TBL[16] = {
    -1.0f, -0.6961928009986877f, -0.5250730514526367f, -0.39491748809814453f,
    -0.28444138169288635f, -0.18477343022823334f, -0.10644006729125977f,
    -0.029167551919817924f, 0.0f, 0.07958029955625534f, 0.16093020141124725f,
    0.24611230194568634f, 0.33791524171829224f, 0.44070982933044434f,
    0.5626170039176941f, 0.7229568362236023f};

__device__ __forceinline__ unsigned short f2bf(float f) {
  uint32_t u = __float_as_uint(f);
  u += 0x7fffu + ((u >> 16) & 1u);   // RNE
  return (unsigned short)(u >> 16);
}

__device__ __forceinline__ void gload_lds16(const void* g, const void* l) {
  __builtin_amdgcn_global_load_lds(
      (const __attribute__((address_space(1))) void*)(uintptr_t)g,
      (__attribute__((address_space(3))) void*)(uint32_t)(uintptr_t)l,
      16, 0, 0);
}

// ---------------- prep 1: x fp32 -> bf16 ----------------
__global__ void convert_x_kernel(const float* __restrict__ x,
                                 unsigned short* __restrict__ xb) {
  const long n8 = (long)M_ROWS * K_DIM / 8;
  for (long t = (long)blockIdx.x * blockDim.x + threadIdx.x; t < n8;
       t += (long)gridDim.x * blockDim.x) {
    const float* p = x + t * 8;
    f32x4 v0 = *(const f32x4*)p;
    f32x4 v1 = *(const f32x4*)(p + 4);
    u16x8 o;
    o[0] = f2bf(v0[0]); o[1] = f2bf(v0[1]); o[2] = f2bf(v0[2]); o[3] = f2bf(v0[3]);
    o[4] = f2bf(v1[0]); o[5] = f2bf(v1[1]); o[6] = f2bf(v1[2]); o[7] = f2bf(v1[3]);
    *(u16x8*)(xb + t * 8) = o;
  }
}

// ---------------- prep 2: NF4 dequant W -> bf16 ----------------
__global__ void dequant_w_kernel(const int* __restrict__ qw,
                                 const int* __restrict__ qs,
                                 const float* __restrict__ qf,
                                 const float* __restrict__ mean,
                                 unsigned short* __restrict__ wb) {
  __shared__ float tbl[16];
  if (threadIdx.x < 16) tbl[threadIdx.x] = NF4_TBL[threadIdx.x];
  __syncthreads();
  const float mu = mean[0];
  const long n8 = (long)N_DIM * K_DIM / 8;
  for (long t = (long)blockIdx.x * blockDim.x + threadIdx.x; t < n8;
       t += (long)gridDim.x * blockDim.x) {
    long f = t * 8;
    int  g = (int)(f >> 6);
    float s = (float)qs[g] / qf[g >> 8] + mu;
    i32x4 q0 = *(const i32x4*)(qw + f);
    i32x4 q1 = *(const i32x4*)(qw + f + 4);
    u16x8 o;
    o[0] = f2bf(tbl[q0[0]] * s); o[1] = f2bf(tbl[q0[1]] * s);
    o[2] = f2bf(tbl[q0[2]] * s); o[3] = f2bf(tbl[q0[3]] * s);
    o[4] = f2bf(tbl[q1[0]] * s); o[5] = f2bf(tbl[q1[1]] * s);
    o[6] = f2bf(tbl[q1[2]] * s); o[7] = f2bf(tbl[q1[3]] * s);
    *(u16x8*)(wb + f) = o;
  }
}

// ---------------- 256x256 8-phase bf16 GEMM:  C = A[M,K] * B[N,K]^T ----------------
// Round-2 proven schedule (double-buffer, per-phase lgkmcnt(0), vmcnt(4) per
// K-tile). NEW: locality-first tile mapping to fix the 10x HBM over-fetch:
//   XCD x (= blockIdx&7), slot j (= blockIdx>>3, 0..171):
//     j < 160: nb = (j>>5)*8 + x, mb = j&31     (nb-superblocks of 8 columns,
//                                                one column per XCD, mb-major)
//     j >= 160: tail super (nb 40..42) redistributed bijectively across XCDs.
// Effect: each XCD's concurrent WGs share ONE B panel (L2-resident); all XCDs
// sweep the SAME mb simultaneously -> instantaneous A working set is a few
// panels -> L3-resident; A re-reads come from L3 not HBM.
#define STG(GP, LB)                                                              \
  gload_lds16((GP) + (long)srow * K_DIM + scol, &LDSbuf[(LB) + wid * 1024]);     \
  gload_lds16((GP) + (long)(64 + srow) * K_DIM + scol,                           \
              &LDSbuf[(LB) + 8192 + wid * 1024]);

__global__ __launch_bounds__(512, 2) void gemm_8phase(
    const unsigned short* __restrict__ xb, const unsigned short* __restrict__ wb,
    float* __restrict__ C) {
  __align__(16) __shared__ unsigned char LDSbuf[131072];

  const int tid = threadIdx.x;
  const int wid = tid >> 6, lane = tid & 63;
  const int wr = wid >> 2, wc = wid & 3;
  const int r16 = lane & 15, hi = lane >> 4;

  // locality-first mapping (see header comment)
  const int bx = (int)blockIdx.x;
  const int x  = bx & 7;            // XCD
  const int j  = bx >> 3;           // slot within XCD, 0..171
  int mb, nb;
  if (j < 160) {
    nb = (j >> 5) * 8 + x;
    mb = j & 31;
  } else {
    int k = x * 12 + (j - 160);     // 0..95 over all XCDs, bijective
    nb = 40 + (k >> 5);
    mb = k & 31;
  }
  const long m0g = (long)mb * BM, n0g = (long)nb * BN;

  // staging coords (per lane)
  const int srow = wid * 8 + (lane >> 3);
  const int scol = ((lane & 7) ^ (lane >> 3)) * 8;   // inverse-swizzled source chunk

  // ds_read coords
  const int aoff = (wr * 128 + r16) * 128;           // + m*2048 (+ parity*32768)
  const int boff = (wc * 64 + r16) * 128;            // + n*2048 (+ 65536 + parity*32768)
  const int kswz0 = ((hi ^ (r16 & 7)) << 4);
  const int kswz1 = kswz0 ^ 64;

  // ---- prologue: A(0)h0,h1  B(0)h0,h1  A(1)h0,h1 ; wait all but A(1) halves ----
  STG(xb + m0g * K_DIM,               0);
  STG(xb + (m0g + 128) * K_DIM,       16384);
  STG(wb + n0g * K_DIM,               65536);
  STG(wb + (n0g + 128) * K_DIM,       65536 + 16384);
  STG(xb + m0g * K_DIM + 64,          32768);
  STG(xb + (m0g + 128) * K_DIM + 64,  32768 + 16384);
  asm volatile("s_waitcnt vmcnt(4)");
  __builtin_amdgcn_sched_barrier(0);
  __builtin_amdgcn_s_barrier();

  bf16x8 af[8][2], bq[2][2];
  f32x4 acc[8][4] = {};

  for (int t = 0; t < KSTEPS; ++t) {
    const int cur = t & 1;
    const int cA = cur * 32768, cB = 65536 + cur * 32768;
    const int nB = 65536 + (cur ^ 1) * 32768;
    const long kB = (long)((t + 1 < KSTEPS ? t + 1 : KSTEPS - 1) * 64);
    const long kA = (long)((t + 2 < KSTEPS ? t + 2 : KSTEPS - 1) * 64);

    // ---------- phase 0: read A m0-3 + B n0-1 ; stage B(t+1)h0 ----------
#pragma unroll
    for (int m = 0; m < 4; ++m) {
      af[m][0] = *(const bf16x8*)&LDSbuf[cA + aoff + m * 2048 + kswz0];
      af[m][1] = *(const bf16x8*)&LDSbuf[cA + aoff + m * 2048 + kswz1];
    }
#pragma unroll
    for (int n = 0; n < 2; ++n) {
      bq[n][0] = *(const bf16x8*)&LDSbuf[cB + boff + n * 2048 + kswz0];
      bq[n][1] = *(const bf16x8*)&LDSbuf[cB + boff + n * 2048 + kswz1];
    }
    STG(wb + n0g * K_DIM + kB, nB);
    __builtin_amdgcn_s_barrier();
    asm volatile("s_waitcnt lgkmcnt(0)");
    __builtin_amdgcn_sched_barrier(0);
    __builtin_amdgcn_s_setprio(1);
#pragma unroll
    for (int m = 0; m < 4; ++m)
#pragma unroll
      for (int n = 0; n < 2; ++n) {
        acc[m][n] = __builtin_amdgcn_mfma_f32_16x16x32_bf16(af[m][0], bq[n][0], acc[m][n], 0, 0, 0);
        acc[m][n] = __builtin_amdgcn_mfma_f32_16x16x32_bf16(af[m][1], bq[n][1], acc[m][n], 0, 0, 0);
      }
    __builtin_amdgcn_s_setprio(0);
    __builtin_amdgcn_s_barrier();
    __builtin_amdgcn_sched_barrier(0);

    // ---------- phase 1: read A m4-7 ; stage B(t+1)h1 ----------
#pragma unroll
    for (int m = 4; m < 8; ++m) {
      af[m][0] = *(const bf16x8*)&LDSbuf[cA + aoff + m * 2048 + kswz0];
      af[m][1] = *(const bf16x8*)&LDSbuf[cA + aoff + m * 2048 + kswz1];
    }
    STG(wb + (n0g + 128) * K_DIM + kB, nB + 16384);
    __builtin_amdgcn_s_barrier();
    asm volatile("s_waitcnt lgkmcnt(0)");
    __builtin_amdgcn_sched_barrier(0);
    __builtin_amdgcn_s_setprio(1);
#pragma unroll
    for (int m = 4; m < 8; ++m)
#pragma unroll
      for (int n = 0; n < 2; ++n) {
        acc[m][n] = __builtin_amdgcn_mfma_f32_16x16x32_bf16(af[m][0], bq[n][0], acc[m][n], 0, 0, 0);
        acc[m][n] = __builtin_amdgcn_mfma_f32_16x16x32_bf16(af[m][1], bq[n][1], acc[m][n], 0, 0, 0);
      }
    __builtin_amdgcn_s_setprio(0);
    __builtin_amdgcn_s_barrier();
    __builtin_amdgcn_sched_barrier(0);

    // ---------- phase 2: read B n2-3 (A m0-3 in regs) ; stage A(t+2)h0 ----------
#pragma unroll
    for (int n = 0; n < 2; ++n) {
      bq[n][0] = *(const bf16x8*)&LDSbuf[cB + boff + (2 + n) * 2048 + kswz0];
      bq[n][1] = *(const bf16x8*)&LDSbuf[cB + boff + (2 + n) * 2048 + kswz1];
    }
    STG(xb + m0g * K_DIM + kA, cA);
    __builtin_amdgcn_s_barrier();
    asm volatile("s_waitcnt lgkmcnt(0)");
    __builtin_amdgcn_sched_barrier(0);
    __builtin_amdgcn_s_setprio(1);
#pragma unroll
    for (int m = 0; m < 4; ++m)
#pragma unroll
      for (int n = 0; n < 2; ++n) {
        acc[m][2 + n] = __builtin_amdgcn_mfma_f32_16x16x32_bf16(af[m][0], bq[n][0], acc[m][2 + n], 0, 0, 0);
        acc[m][2 + n] = __builtin_amdgcn_mfma_f32_16x16x32_bf16(af[m][1], bq[n][1], acc[m][2 + n], 0, 0, 0);
      }
    __builtin_amdgcn_s_setprio(0);
    __builtin_amdgcn_s_barrier();
    __builtin_amdgcn_sched_barrier(0);

    // ---------- phase 3: A m4-7 x B n2-3 (all regs) ; stage A(t+2)h1 ----------
    STG(xb + (m0g + 128) * K_DIM + kA, cA + 16384);
    __builtin_amdgcn_s_barrier();
    asm volatile("s_waitcnt lgkmcnt(0)");
    __builtin_amdgcn_sched_barrier(0);
    __builtin_amdgcn_s_setprio(1);
#pragma unroll
    for (int m = 4; m < 8; ++m)
#pragma unroll
      for (int n = 0; n < 2; ++n) {
        acc[m][2 + n] = __builtin_amdgcn_mfma_f32_16x16x32_bf16(af[m][0], bq[n][0], acc[m][2 + n], 0, 0, 0);
        acc[m][2 + n] = __builtin_amdgcn_mfma_f32_16x16x32_bf16(af[m][1], bq[n][1], acc[m][2 + n], 0, 0, 0);
      }
    __builtin_amdgcn_s_setprio(0);
    asm volatile("s_waitcnt vmcnt(4)");   // counted: only A(t+2) halves may remain in flight
    __builtin_amdgcn_sched_barrier(0);
    __builtin_amdgcn_s_barrier();
    __builtin_amdgcn_sched_barrier(0);
  }

  // ---- epilogue: C/D layout col=lane&15, row=hi*4+reg; nontemporal ----
  const long crow = m0g + wr * 128 + hi * 4;
  const long ccol = n0g + wc * 64 + r16;
#pragma unroll
  for (int m = 0; m < 8; ++m)
#pragma unroll
    for (int n = 0; n < 4; ++n)
#pragma unroll
      for (int r = 0; r < 4; ++r)
        __builtin_nontemporal_store(
            acc[m][n][r], &C[(crow + m * 16 + r) * N_DIM + ccol + n * 16]);
}

// ---------------- fallback (no workspace): fused 128^2 kernel ----------------
__global__ __launch_bounds__(256) void gemm_fallback(
    const float* __restrict__ Xf, const int* __restrict__ qw,
    const int* __restrict__ qs, const float* __restrict__ qf,
    const float* __restrict__ meanp, float* __restrict__ C) {
  __shared__ unsigned short As[128 * 64];
  __shared__ unsigned short Bs[128 * 64];
  __shared__ float tbl[16];
  const int tid = threadIdx.x;
  if (tid < 16) tbl[tid] = NF4_TBL[tid];
  const float mu = meanp[0];
  const int nwg = (M_ROWS / 128) * (N_DIM / 128);
  const int wg = ((int)blockIdx.x & 7) * (nwg / 8) + ((int)blockIdx.x >> 3);
  const int mb = wg % (M_ROWS / 128), nb = wg / (M_ROWS / 128);
  const int m0 = mb * 128, n0 = nb * 128;
  const int wid = tid >> 6, lane = tid & 63;
  const int wr = wid >> 1, wcc = wid & 1;
  const int r16 = lane & 15, hi = lane >> 4;
  f32x4 acc[4][4] = {};
  for (int t = 0; t < KSTEPS; ++t) {
    const int k0 = t * 64;
    __syncthreads();
#pragma unroll
    for (int i = 0; i < 4; ++i) {
      int gi = i * 256 + tid;
      int row = gi >> 3, kq = (gi & 7) * 8;
      const float* px = Xf + (long)(m0 + row) * K_DIM + k0 + kq;
      f32x4 v0 = *(const f32x4*)px;
      f32x4 v1 = *(const f32x4*)(px + 4);
      u16x8 o;
      o[0] = f2bf(v0[0]); o[1] = f2bf(v0[1]); o[2] = f2bf(v0[2]); o[3] = f2bf(v0[3]);
      o[4] = f2bf(v1[0]); o[5] = f2bf(v1[1]); o[6] = f2bf(v1[2]); o[7] = f2bf(v1[3]);
      *(u16x8*)&As[row * 64 + kq] = o;
    }
#pragma unroll
    for (int i = 0; i < 4; ++i) {
      int gi = i * 256 + tid;
      int row = gi >> 3, kq = (gi & 7) * 8;
      const int* pq = qw + (long)(n0 + row) * K_DIM + k0 + kq;
      i32x4 q0 = *(const i32x4*)pq;
      i32x4 q1 = *(const i32x4*)(pq + 4);
      int g = (n0 + row) * (K_DIM / 64) + t;
      float s = (float)qs[g] / qf[g >> 8] + mu;
      u16x8 o;
      o[0] = f2bf(tbl[q0[0]] * s); o[1] = f2bf(tbl[q0[1]] * s);
      o[2] = f2bf(tbl[q0[2]] * s); o[3] = f2bf(tbl[q0[3]] * s);
      o[4] = f2bf(tbl[q1[0]] * s); o[5] = f2bf(tbl[q1[1]] * s);
      o[6] = f2bf(tbl[q1[2]] * s); o[7] = f2bf(tbl[q1[3]] * s);
      *(u16x8*)&Bs[row * 64 + kq] = o;
    }
    __syncthreads();
    bf16x8 afr[4][2], bfr[4][2];
#pragma unroll
    for (int i = 0; i < 4; ++i)
#pragma unroll
      for (int h = 0; h < 2; ++h) {
        afr[i][h] = *(const bf16x8*)&As[(wr * 64 + i * 16 + r16) * 64 + h * 32 + hi * 8];
        bfr[i][h] = *(const bf16x8*)&Bs[(wcc * 64 + i * 16 + r16) * 64 + h * 32 + hi * 8];
      }
#pragma unroll
    for (int i = 0; i < 4; ++i)
#pragma unroll
      for (int j = 0; j < 4; ++j) {
        acc[i][j] = __builtin_amdgcn_mfma_f32_16x16x32_bf16(afr[i][0], bfr[j][0], acc[i][j], 0, 0, 0);
        acc[i][j] = __builtin_amdgcn_mfma_f32_16x16x32_bf16(afr[i][1], bfr[j][1], acc[i][j], 0, 0, 0);
      }
  }
  const int crow = m0 + wr * 64 + hi * 4;
  const int ccol = n0 + wcc * 64 + r16;
#pragma unroll
  for (int i = 0; i < 4; ++i)
#pragma unroll
    for (int j = 0; j < 4; ++j)
#pragma unroll
      for (int r = 0; r < 4; ++r)
        C[(long)(crow + i * 16 + r) * N_DIM + (ccol + j * 16)] = acc[i][j][r];
}

extern "C" void kernel_launch(void* const* d_in, const int* in_sizes, int n_in,
                              void* d_out, int out_size, void* d_ws, size_t ws_size,
                              hipStream_t stream) {
  const float* x    = (const float*)d_in[0];
  const int*   qw   = (const int*)d_in[1];
  const int*   qs   = (const int*)d_in[2];
  const float* qf   = (const float*)d_in[3];
  const float* mean = (const float*)d_in[4];
  float* out = (float*)d_out;

  const size_t xb_bytes = (size_t)M_ROWS * K_DIM * 2;  // 64 MiB
  const size_t wb_bytes = (size_t)N_DIM * K_DIM * 2;   // 86 MiB

  if (ws_size >= xb_bytes + wb_bytes) {
    unsigned short* xb = (unsigned short*)d_ws;
    unsigned short* wb = (unsigned short*)((char*)d_ws + xb_bytes);
    convert_x_kernel<<<4096, 256, 0, stream>>>(x, xb);
    dequant_w_kernel<<<4096, 256, 0, stream>>>(qw, qs, qf, mean, wb);
    gemm_8phase<<<NWG, 512, 0, stream>>>(xb, wb, out);
  } else {
    gemm_fallback<<<(M_ROWS / 128) * (N_DIM / 128), 256, 0, stream>>>(
        x, qw, qs, qf, mean, out);
  }
}

// Round 6
// 777.174 us; speedup vs baseline: 1.0699x; 1.0699x over previous
//
#include <hip/hip_runtime.h>
#include <stdint.h>

#define M_ROWS 8192
#define K_DIM  4096
#define N_DIM  11008
#define KSTEPS (K_DIM / 64)      // 64 K-tiles of BK=64

// ---- 256x256 geometry, 8 waves (2M x 4N), per-wave output 128x64 ----
#define BM 256
#define BN 256
#define MBLKS (M_ROWS / BM)      // 32
#define NBLKS (N_DIM / BN)       // 43
#define NWG   (MBLKS * NBLKS)    // 1376 (%8==0 -> simple XCD swizzle bijective)

typedef __attribute__((ext_vector_type(4))) float          f32x4;
typedef __attribute__((ext_vector_type(8))) __bf16         bf16x8;
typedef __attribute__((ext_vector_type(4))) int            i32x4;
typedef __attribute__((ext_vector_type(8))) unsigned short u16x8;

__constant__ float NF4_TBL[16] = {
    -1.0f, -0.6961928009986877f, -0.5250730514526367f, -0.39491748809814453f,
    -0.28444138169288635f, -0.18477343022823334f, -0.10644006729125977f,
    -0.029167551919817924f, 0.0f, 0.07958029955625534f, 0.16093020141124725f,
    0.24611230194568634f, 0.33791524171829224f, 0.44070982933044434f,
    0.5626170039176941f, 0.7229568362236023f};

__device__ __forceinline__ unsigned short f2bf(float f) {
  uint32_t u = __float_as_uint(f);
  u += 0x7fffu + ((u >> 16) & 1u);   // RNE
  return (unsigned short)(u >> 16);
}

__device__ __forceinline__ void gload_lds16(const void* g, const void* l) {
  __builtin_amdgcn_global_load_lds(
      (const __attribute__((address_space(1))) void*)(uintptr_t)g,
      (__attribute__((address_space(3))) void*)(uint32_t)(uintptr_t)l,
      16, 0, 0);
}

// ---------------- prep 1: x fp32 -> bf16 ----------------
__global__ void convert_x_kernel(const float* __restrict__ x,
                                 unsigned short* __restrict__ xb) {
  const long n8 = (long)M_ROWS * K_DIM / 8;
  for (long t = (long)blockIdx.x * blockDim.x + threadIdx.x; t < n8;
       t += (long)gridDim.x * blockDim.x) {
    const float* p = x + t * 8;
    f32x4 v0 = *(const f32x4*)p;
    f32x4 v1 = *(const f32x4*)(p + 4);
    u16x8 o;
    o[0] = f2bf(v0[0]); o[1] = f2bf(v0[1]); o[2] = f2bf(v0[2]); o[3] = f2bf(v0[3]);
    o[4] = f2bf(v1[0]); o[5] = f2bf(v1[1]); o[6] = f2bf(v1[2]); o[7] = f2bf(v1[3]);
    *(u16x8*)(xb + t * 8) = o;
  }
}

// ---------------- prep 2: NF4 dequant W -> bf16 ----------------
__global__ void dequant_w_kernel(const int* __restrict__ qw,
                                 const int* __restrict__ qs,
                                 const float* __restrict__ qf,
                                 const float* __restrict__ mean,
                                 unsigned short* __restrict__ wb) {
  __shared__ float tbl[16];
  if (threadIdx.x < 16) tbl[threadIdx.x] = NF4_TBL[threadIdx.x];
  __syncthreads();
  const float mu = mean[0];
  const long n8 = (long)N_DIM * K_DIM / 8;
  for (long t = (long)blockIdx.x * blockDim.x + threadIdx.x; t < n8;
       t += (long)gridDim.x * blockDim.x) {
    long f = t * 8;
    int  g = (int)(f >> 6);
    float s = (float)qs[g] / qf[g >> 8] + mu;
    i32x4 q0 = *(const i32x4*)(qw + f);
    i32x4 q1 = *(const i32x4*)(qw + f + 4);
    u16x8 o;
    o[0] = f2bf(tbl[q0[0]] * s); o[1] = f2bf(tbl[q0[1]] * s);
    o[2] = f2bf(tbl[q0[2]] * s); o[3] = f2bf(tbl[q0[3]] * s);
    o[4] = f2bf(tbl[q1[0]] * s); o[5] = f2bf(tbl[q1[1]] * s);
    o[6] = f2bf(tbl[q1[2]] * s); o[7] = f2bf(tbl[q1[3]] * s);
    *(u16x8*)(wb + f) = o;
  }
}

// ---------------- 256x256 one-barrier-per-tile bf16 GEMM:  C = A * B^T ----------------
// LDS 160 KiB: A TRIPLE buffer [3][256][64]bf16 at 0/32768/65536 (slot t%3),
//              B double buffer [2][256][64]bf16 at 98304+parity*32768.
// Per K-tile: 1 s_barrier + 1 counted vmcnt(4). 8 MFMA clusters (8 each) with
// one-cluster-lookahead ds_reads; compiler inserts progressive lgkmcnt between
// a cluster's reads and the next cluster's MFMAs (m97 mechanism). Waves drift
// within the tile so LDS and MFMA pipes overlap across waves.
// Stage plan (tile t): B(t+1)->parity^1 at c0,c1; A(t+2)->slot (t+2)%3 at c2,c3.
// Ledger: slot (t+2)%3 was last read at tile t-1 (reads complete before t-1's
// MFMAs, which precede the t-1/t barrier) -> stage-after-barrier is race-free.
// vmcnt(4) before the tile-end barrier forces everything except A(t+2)'s 4
// loads to have landed, per-wave, BEFORE the barrier -> all waves' stages for
// tile t+1 are visible to all waves at t+1 start.
#define STG(GP, LB)                                                              \
  gload_lds16((GP) + (long)srow * K_DIM + scol, &LDSbuf[(LB) + wid * 1024]);     \
  gload_lds16((GP) + (long)(64 + srow) * K_DIM + scol,                           \
              &LDSbuf[(LB) + 8192 + wid * 1024]);

#define SB __builtin_amdgcn_sched_barrier(0)

// read one m-pair (2 frags x 2 halves) from A slot SA
#define RD_A2(DST, MB, SA)                                                        \
  DST[0][0] = *(const bf16x8*)&LDSbuf[(SA) + aoff + (MB) * 2048 + kswz0];         \
  DST[0][1] = *(const bf16x8*)&LDSbuf[(SA) + aoff + (MB) * 2048 + kswz1];         \
  DST[1][0] = *(const bf16x8*)&LDSbuf[(SA) + aoff + ((MB) + 1) * 2048 + kswz0];   \
  DST[1][1] = *(const bf16x8*)&LDSbuf[(SA) + aoff + ((MB) + 1) * 2048 + kswz1];

// read one n-pair of B into bq[NB],bq[NB+1]
#define RD_B2(NB, CB)                                                             \
  bq[NB][0]     = *(const bf16x8*)&LDSbuf[(CB) + boff + (NB) * 2048 + kswz0];     \
  bq[NB][1]     = *(const bf16x8*)&LDSbuf[(CB) + boff + (NB) * 2048 + kswz1];     \
  bq[NB + 1][0] = *(const bf16x8*)&LDSbuf[(CB) + boff + ((NB) + 1) * 2048 + kswz0];\
  bq[NB + 1][1] = *(const bf16x8*)&LDSbuf[(CB) + boff + ((NB) + 1) * 2048 + kswz1];

// 4 MFMA: one m-frag x one n-frag over both k-halves... grouped per (m,n)
#define MFP(MI, AF, AI, NI)                                                       \
  acc[MI][NI] = __builtin_amdgcn_mfma_f32_16x16x32_bf16(AF[AI][0], bq[NI][0], acc[MI][NI], 0, 0, 0); \
  acc[MI][NI] = __builtin_amdgcn_mfma_f32_16x16x32_bf16(AF[AI][1], bq[NI][1], acc[MI][NI], 0, 0, 0);

// one cluster: m-pair (MB,MB+1 via AF) x n-pair (N0,N0+1) = 8 MFMA
#define CLUSTER(MB, AF, N0)                                                       \
  __builtin_amdgcn_s_setprio(1);                                                  \
  MFP(MB, AF, 0, N0) MFP(MB, AF, 1, N0)                                           \
  MFP((MB) + 1 - 1 + 1, AF, 1, (N0) + 1) /*placeholder*/                          \
  __builtin_amdgcn_s_setprio(0);

__global__ __launch_bounds__(512, 2) void gemm_pipe(
    const unsigned short* __restrict__ xb, const unsigned short* __restrict__ wb,
    float* __restrict__ C) {
  __align__(16) __shared__ unsigned char LDSbuf[163840];   // 96K A(3) + 64K B(2)

  const int tid = threadIdx.x;
  const int wid = tid >> 6, lane = tid & 63;
  const int wr = wid >> 2, wc = wid & 3;
  const int r16 = lane & 15, hi = lane >> 4;

  // XCD-aware bijective swizzle (NWG % 8 == 0) — round-2 proven mapping
  const int wg = ((int)blockIdx.x & 7) * (NWG / 8) + ((int)blockIdx.x >> 3);
  const int mb = wg % MBLKS, nb = wg / MBLKS;
  const long m0g = (long)mb * BM, n0g = (long)nb * BN;

  // staging coords (per lane); T2: linear LDS dest, inverse-swizzled source
  const int srow = wid * 8 + (lane >> 3);
  const int scol = ((lane & 7) ^ (lane >> 3)) * 8;

  // ds_read coords (T2 swizzle on read)
  const int aoff = (wr * 128 + r16) * 128;
  const int boff = (wc * 64 + r16) * 128;
  const int kswz0 = ((hi ^ (r16 & 7)) << 4);
  const int kswz1 = kswz0 ^ 64;

  // ---- prologue: A(0)->slot0, B(0)->par0, A(1)->slot1; wait all but A(1) ----
  STG(xb + m0g * K_DIM,              0);
  STG(xb + (m0g + 128) * K_DIM,      16384);
  STG(wb + n0g * K_DIM,              98304);
  STG(wb + (n0g + 128) * K_DIM,      98304 + 16384);
  STG(xb + m0g * K_DIM + 64,         32768);
  STG(xb + (m0g + 128) * K_DIM + 64, 32768 + 16384);
  asm volatile("s_waitcnt vmcnt(4)");
  __builtin_amdgcn_sched_barrier(0);
  __builtin_amdgcn_s_barrier();

  bf16x8 af_a[2][2], af_b[2][2], bq[4][2];
  f32x4 acc[8][4] = {};

  int sAr = 0, sAn = 32768, sAs = 65536;   // A slots: read(t), read(t+1), stage(t+2)

  for (int t = 0; t < KSTEPS; ++t) {
    const int cur = t & 1;
    const int cB = 98304 + cur * 32768;
    const int nB = 98304 + (cur ^ 1) * 32768;
    const long kB = (long)((t + 1 < KSTEPS ? t + 1 : KSTEPS - 1) * 64);
    const long kA = (long)((t + 2 < KSTEPS ? t + 2 : KSTEPS - 1) * 64);

    // ---- pre: A m0-1, B n0-1 ----
    RD_A2(af_a, 0, sAr);
    RD_B2(0, cB);
    SB;
    // ---- c0 [m01 x n01]; read B n23; stage B(t+1)h0 ----
    RD_B2(2, cB);
    STG(wb + n0g * K_DIM + kB, nB);
    __builtin_amdgcn_s_setprio(1);
    MFP(0, af_a, 0, 0) MFP(1, af_a, 1, 0) MFP(0, af_a, 0, 1) MFP(1, af_a, 1, 1)
    __builtin_amdgcn_s_setprio(0);
    SB;
    // ---- c1 [m01 x n23]; read A m23; stage B(t+1)h1 ----
    RD_A2(af_b, 2, sAr);
    STG(wb + (n0g + 128) * K_DIM + kB, nB + 16384);
    __builtin_amdgcn_s_setprio(1);
    MFP(0, af_a, 0, 2) MFP(1, af_a, 1, 2) MFP(0, af_a, 0, 3) MFP(1, af_a, 1, 3)
    __builtin_amdgcn_s_setprio(0);
    SB;
    // ---- c2 [m23 x n23]; stage A(t+2)h0 ----
    STG(xb + m0g * K_DIM + kA, sAs);
    __builtin_amdgcn_s_setprio(1);
    MFP(2, af_b, 0, 2) MFP(3, af_b, 1, 2) MFP(2, af_b, 0, 3) MFP(3, af_b, 1, 3)
    __builtin_amdgcn_s_setprio(0);
    SB;
    // ---- c3 [m23 x n01]; read A m45; stage A(t+2)h1 ----
    RD_A2(af_a, 4, sAr);
    STG(xb + (m0g + 128) * K_DIM + kA, sAs + 16384);
    __builtin_amdgcn_s_setprio(1);
    MFP(2, af_b, 0, 0) MFP(3, af_b, 1, 0) MFP(2, af_b, 0, 1) MFP(3, af_b, 1, 1)
    __builtin_amdgcn_s_setprio(0);
    SB;
    // ---- c4 [m45 x n01] ----
    __builtin_amdgcn_s_setprio(1);
    MFP(4, af_a, 0, 0) MFP(5, af_a, 1, 0) MFP(4, af_a, 0, 1) MFP(5, af_a, 1, 1)
    __builtin_amdgcn_s_setprio(0);
    SB;
    // ---- c5 [m45 x n23]; read A m67 ----
    RD_A2(af_b, 6, sAr);
    __builtin_amdgcn_s_setprio(1);
    MFP(4, af_a, 0, 2) MFP(5, af_a, 1, 2) MFP(4, af_a, 0, 3) MFP(5, af_a, 1, 3)
    __builtin_amdgcn_s_setprio(0);
    SB;
    // ---- c6 [m67 x n23] ----
    __builtin_amdgcn_s_setprio(1);
    MFP(6, af_b, 0, 2) MFP(7, af_b, 1, 2) MFP(6, af_b, 0, 3) MFP(7, af_b, 1, 3)
    __builtin_amdgcn_s_setprio(0);
    SB;
    // ---- c7 [m67 x n01] ----
    __builtin_amdgcn_s_setprio(1);
    MFP(6, af_b, 0, 0) MFP(7, af_b, 1, 0) MFP(6, af_b, 0, 1) MFP(7, af_b, 1, 1)
    __builtin_amdgcn_s_setprio(0);
    // ---- tile boundary: ONE counted vmcnt + ONE barrier ----
    asm volatile("s_waitcnt vmcnt(4)");   // only A(t+2)'s 4 stages may remain
    __builtin_amdgcn_sched_barrier(0);
    __builtin_amdgcn_s_barrier();
    __builtin_amdgcn_sched_barrier(0);

    int tmp = sAr; sAr = sAn; sAn = sAs; sAs = tmp;   // rotate A slots
  }

  // ---- epilogue: C/D layout col=lane&15, row=hi*4+reg; nontemporal ----
  const long crow = m0g + wr * 128 + hi * 4;
  const long ccol = n0g + wc * 64 + r16;
#pragma unroll
  for (int m = 0; m < 8; ++m)
#pragma unroll
    for (int n = 0; n < 4; ++n)
#pragma unroll
      for (int r = 0; r < 4; ++r)
        __builtin_nontemporal_store(
            acc[m][n][r], &C[(crow + m * 16 + r) * N_DIM + ccol + n * 16]);
}

// ---------------- fallback (no workspace): fused 128^2 kernel ----------------
__global__ __launch_bounds__(256) void gemm_fallback(
    const float* __restrict__ Xf, const int* __restrict__ qw,
    const int* __restrict__ qs, const float* __restrict__ qf,
    const float* __restrict__ meanp, float* __restrict__ C) {
  __shared__ unsigned short As[128 * 64];
  __shared__ unsigned short Bs[128 * 64];
  __shared__ float tbl[16];
  const int tid = threadIdx.x;
  if (tid < 16) tbl[tid] = NF4_TBL[tid];
  const float mu = meanp[0];
  const int nwg = (M_ROWS / 128) * (N_DIM / 128);
  const int wg = ((int)blockIdx.x & 7) * (nwg / 8) + ((int)blockIdx.x >> 3);
  const int mbf = wg % (M_ROWS / 128), nbf = wg / (M_ROWS / 128);
  const int m0 = mbf * 128, n0 = nbf * 128;
  const int wid = tid >> 6, lane = tid & 63;
  const int wrf = wid >> 1, wcc = wid & 1;
  const int r16 = lane & 15, hi = lane >> 4;
  f32x4 acc[4][4] = {};
  for (int t = 0; t < KSTEPS; ++t) {
    const int k0 = t * 64;
    __syncthreads();
#pragma unroll
    for (int i = 0; i < 4; ++i) {
      int gi = i * 256 + tid;
      int row = gi >> 3, kq = (gi & 7) * 8;
      const float* px = Xf + (long)(m0 + row) * K_DIM + k0 + kq;
      f32x4 v0 = *(const f32x4*)px;
      f32x4 v1 = *(const f32x4*)(px + 4);
      u16x8 o;
      o[0] = f2bf(v0[0]); o[1] = f2bf(v0[1]); o[2] = f2bf(v0[2]); o[3] = f2bf(v0[3]);
      o[4] = f2bf(v1[0]); o[5] = f2bf(v1[1]); o[6] = f2bf(v1[2]); o[7] = f2bf(v1[3]);
      *(u16x8*)&As[row * 64 + kq] = o;
    }
#pragma unroll
    for (int i = 0; i < 4; ++i) {
      int gi = i * 256 + tid;
      int row = gi >> 3, kq = (gi & 7) * 8;
      const int* pq = qw + (long)(n0 + row) * K_DIM + k0 + kq;
      i32x4 q0 = *(const i32x4*)pq;
      i32x4 q1 = *(const i32x4*)(pq + 4);
      int g = (n0 + row) * (K_DIM / 64) + t;
      float s = (float)qs[g] / qf[g >> 8] + mu;
      u16x8 o;
      o[0] = f2bf(tbl[q0[0]] * s); o[1] = f2bf(tbl[q0[1]] * s);
      o[2] = f2bf(tbl[q0[2]] * s); o[3] = f2bf(tbl[q0[3]] * s);
      o[4] = f2bf(tbl[q1[0]] * s); o[5] = f2bf(tbl[q1[1]] * s);
      o[6] = f2bf(tbl[q1[2]] * s); o[7] = f2bf(tbl[q1[3]] * s);
      *(u16x8*)&Bs[row * 64 + kq] = o;
    }
    __syncthreads();
    bf16x8 afr[4][2], bfr[4][2];
#pragma unroll
    for (int i = 0; i < 4; ++i)
#pragma unroll
      for (int h = 0; h < 2; ++h) {
        afr[i][h] = *(const bf16x8*)&As[(wrf * 64 + i * 16 + r16) * 64 + h * 32 + hi * 8];
        bfr[i][h] = *(const bf16x8*)&Bs[(wcc * 64 + i * 16 + r16) * 64 + h * 32 + hi * 8];
      }
#pragma unroll
    for (int i = 0; i < 4; ++i)
#pragma unroll
      for (int j = 0; j < 4; ++j) {
        acc[i][j] = __builtin_amdgcn_mfma_f32_16x16x32_bf16(afr[i][0], bfr[j][0], acc[i][j], 0, 0, 0);
        acc[i][j] = __builtin_amdgcn_mfma_f32_16x16x32_bf16(afr[i][1], bfr[j][1], acc[i][j], 0, 0, 0);
      }
  }
  const int crow = m0 + wrf * 64 + hi * 4;
  const int ccol = n0 + wcc * 64 + r16;
#pragma unroll
  for (int i = 0; i < 4; ++i)
#pragma unroll
    for (int j = 0; j < 4; ++j)
#pragma unroll
      for (int r = 0; r < 4; ++r)
        C[(long)(crow + i * 16 + r) * N_DIM + (ccol + j * 16)] = acc[i][j][r];
}

extern "C" void kernel_launch(void* const* d_in, const int* in_sizes, int n_in,
                              void* d_out, int out_size, void* d_ws, size_t ws_size,
                              hipStream_t stream) {
  const float* x    = (const float*)d_in[0];
  const int*   qw   = (const int*)d_in[1];
  const int*   qs   = (const int*)d_in[2];
  const float* qf   = (const float*)d_in[3];
  const float* mean = (const float*)d_in[4];
  float* out = (float*)d_out;

  const size_t xb_bytes = (size_t)M_ROWS * K_DIM * 2;  // 64 MiB
  const size_t wb_bytes = (size_t)N_DIM * K_DIM * 2;   // 86 MiB

  if (ws_size >= xb_bytes + wb_bytes) {
    unsigned short* xb = (unsigned short*)d_ws;
    unsigned short* wb = (unsigned short*)((char*)d_ws + xb_bytes);
    convert_x_kernel<<<4096, 256, 0, stream>>>(x, xb);
    dequant_w_kernel<<<4096, 256, 0, stream>>>(qw, qs, qf, mean, wb);
    gemm_pipe<<<NWG, 512, 0, stream>>>(xb, wb, out);
  } else {
    gemm_fallback<<<(M_ROWS / 128) * (N_DIM / 128), 256, 0, stream>>>(
        x, qw, qs, qf, mean, out);
  }
}

// Round 7
// 693.420 us; speedup vs baseline: 1.1992x; 1.1208x over previous
//
#include <hip/hip_runtime.h>
#include <stdint.h>

#define M_ROWS 8192
#define K_DIM  4096
#define N_DIM  11008
#define KSTEPS (K_DIM / 64)      // 64 K-tiles of BK=64

// ---- 256x256 geometry, 8 waves (2M x 4N), per-wave output 128x64 ----
#define BM 256
#define BN 256
#define MBLKS (M_ROWS / BM)      // 32
#define NBLKS (N_DIM / BN)       // 43
#define NWG   (MBLKS * NBLKS)    // 1376

typedef __attribute__((ext_vector_type(4))) float          f32x4;
typedef __attribute__((ext_vector_type(8))) __bf16         bf16x8;
typedef __attribute__((ext_vector_type(4))) int            i32x4;
typedef __attribute__((ext_vector_type(8))) unsigned short u16x8;

__constant__ float NF4_TBL[16] = {
    -1.0f, -0.6961928009986877f, -0.5250730514526367f, -0.39491748809814453f,
    -0.28444138169288635f, -0.18477343022823334f, -0.10644006729125977f,
    -0.029167551919817924f, 0.0f, 0.07958029955625534f, 0.16093020141124725f,
    0.24611230194568634f, 0.33791524171829224f, 0.44070982933044434f,
    0.5626170039176941f, 0.7229568362236023f};

__device__ __forceinline__ unsigned short f2bf(float f) {
  uint32_t u = __float_as_uint(f);
  u += 0x7fffu + ((u >> 16) & 1u);   // RNE
  return (unsigned short)(u >> 16);
}

__device__ __forceinline__ void gload_lds16(const void* g, const void* l) {
  __builtin_amdgcn_global_load_lds(
      (const __attribute__((address_space(1))) void*)(uintptr_t)g,
      (__attribute__((address_space(3))) void*)(uint32_t)(uintptr_t)l,
      16, 0, 0);
}

// ---------------- prep 1: x fp32 -> bf16 ----------------
__global__ void convert_x_kernel(const float* __restrict__ x,
                                 unsigned short* __restrict__ xb) {
  const long n8 = (long)M_ROWS * K_DIM / 8;
  for (long t = (long)blockIdx.x * blockDim.x + threadIdx.x; t < n8;
       t += (long)gridDim.x * blockDim.x) {
    const float* p = x + t * 8;
    f32x4 v0 = *(const f32x4*)p;
    f32x4 v1 = *(const f32x4*)(p + 4);
    u16x8 o;
    o[0] = f2bf(v0[0]); o[1] = f2bf(v0[1]); o[2] = f2bf(v0[2]); o[3] = f2bf(v0[3]);
    o[4] = f2bf(v1[0]); o[5] = f2bf(v1[1]); o[6] = f2bf(v1[2]); o[7] = f2bf(v1[3]);
    *(u16x8*)(xb + t * 8) = o;
  }
}

// ---------------- prep 2: NF4 dequant W -> bf16 ----------------
__global__ void dequant_w_kernel(const int* __restrict__ qw,
                                 const int* __restrict__ qs,
                                 const float* __restrict__ qf,
                                 const float* __restrict__ mean,
                                 unsigned short* __restrict__ wb) {
  __shared__ float tbl[16];
  if (threadIdx.x < 16) tbl[threadIdx.x] = NF4_TBL[threadIdx.x];
  __syncthreads();
  const float mu = mean[0];
  const long n8 = (long)N_DIM * K_DIM / 8;
  for (long t = (long)blockIdx.x * blockDim.x + threadIdx.x; t < n8;
       t += (long)gridDim.x * blockDim.x) {
    long f = t * 8;
    int  g = (int)(f >> 6);
    float s = (float)qs[g] / qf[g >> 8] + mu;
    i32x4 q0 = *(const i32x4*)(qw + f);
    i32x4 q1 = *(const i32x4*)(qw + f + 4);
    u16x8 o;
    o[0] = f2bf(tbl[q0[0]] * s); o[1] = f2bf(tbl[q0[1]] * s);
    o[2] = f2bf(tbl[q0[2]] * s); o[3] = f2bf(tbl[q0[3]] * s);
    o[4] = f2bf(tbl[q1[0]] * s); o[5] = f2bf(tbl[q1[1]] * s);
    o[6] = f2bf(tbl[q1[2]] * s); o[7] = f2bf(tbl[q1[3]] * s);
    *(u16x8*)(wb + f) = o;
  }
}

// ---------------- 256x256 one-barrier-per-tile bf16 GEMM:  C = A * B^T ----------------
// Schedule identical to round 6 (best measured). NEW: supertile mapping to cut
// L2-fill traffic. FETCH model (validated by R2==R5 fetch invariance): per
// K-step, an XCD's 32 concurrent WGs dedup staging only within their
// concurrency window; fill = (#distinct A panels + #distinct B panels)*32KB.
// Old maps: 32mb x 1nb -> 1.03 MB/XCD/step. New: 8mb x 4nb supertiles ->
// 384 KB/XCD/step. Seq order: nbg (11 groups of 4 cols; last has 3) -> mbg (4
// groups of 8 rows) -> 32 (or 24) WGs inside. XCD x takes seq[x*172..+172).
#define STG(GP, LB)                                                              \
  gload_lds16((GP) + (long)srow * K_DIM + scol, &LDSbuf[(LB) + wid * 1024]);     \
  gload_lds16((GP) + (long)(64 + srow) * K_DIM + scol,                           \
              &LDSbuf[(LB) + 8192 + wid * 1024]);

#define SB __builtin_amdgcn_sched_barrier(0)

#define RD_A2(DST, MB, SA)                                                        \
  DST[0][0] = *(const bf16x8*)&LDSbuf[(SA) + aoff + (MB) * 2048 + kswz0];         \
  DST[0][1] = *(const bf16x8*)&LDSbuf[(SA) + aoff + (MB) * 2048 + kswz1];         \
  DST[1][0] = *(const bf16x8*)&LDSbuf[(SA) + aoff + ((MB) + 1) * 2048 + kswz0];   \
  DST[1][1] = *(const bf16x8*)&LDSbuf[(SA) + aoff + ((MB) + 1) * 2048 + kswz1];

#define RD_B2(NB, CB)                                                             \
  bq[NB][0]     = *(const bf16x8*)&LDSbuf[(CB) + boff + (NB) * 2048 + kswz0];     \
  bq[NB][1]     = *(const bf16x8*)&LDSbuf[(CB) + boff + (NB) * 2048 + kswz1];     \
  bq[NB + 1][0] = *(const bf16x8*)&LDSbuf[(CB) + boff + ((NB) + 1) * 2048 + kswz0];\
  bq[NB + 1][1] = *(const bf16x8*)&LDSbuf[(CB) + boff + ((NB) + 1) * 2048 + kswz1];

#define MFP(MI, AF, AI, NI)                                                       \
  acc[MI][NI] = __builtin_amdgcn_mfma_f32_16x16x32_bf16(AF[AI][0], bq[NI][0], acc[MI][NI], 0, 0, 0); \
  acc[MI][NI] = __builtin_amdgcn_mfma_f32_16x16x32_bf16(AF[AI][1], bq[NI][1], acc[MI][NI], 0, 0, 0);

__global__ __launch_bounds__(512, 2) void gemm_pipe(
    const unsigned short* __restrict__ xb, const unsigned short* __restrict__ wb,
    float* __restrict__ C) {
  __align__(16) __shared__ unsigned char LDSbuf[163840];   // 96K A(3) + 64K B(2)

  const int tid = threadIdx.x;
  const int wid = tid >> 6, lane = tid & 63;
  const int wr = wid >> 2, wc = wid & 3;
  const int r16 = lane & 15, hi = lane >> 4;

  // ---- supertile mapping: 8mb x 4nb concurrent per XCD (see header) ----
  const int p = ((int)blockIdx.x & 7) * (NWG / 8) + ((int)blockIdx.x >> 3);
  int mb, nb;
  if (p < 1280) {                 // 10 full nbg x 4 mbg x 32
    const int nbg = p >> 7;       // 0..9
    const int rem = p & 127;
    const int mbg = rem >> 5;     // 0..3
    const int s   = rem & 31;
    mb = mbg * 8 + (s & 7);
    nb = nbg * 4 + (s >> 3);
  } else {                        // ragged tail: nb 40..42, 4 mbg x 24
    const int q   = p - 1280;     // 0..95
    const int mbg = q / 24;
    const int s   = q % 24;
    mb = mbg * 8 + (s & 7);
    nb = 40 + (s >> 3);
  }
  const long m0g = (long)mb * BM, n0g = (long)nb * BN;

  // staging coords (per lane); T2: linear LDS dest, inverse-swizzled source
  const int srow = wid * 8 + (lane >> 3);
  const int scol = ((lane & 7) ^ (lane >> 3)) * 8;

  // ds_read coords (T2 swizzle on read)
  const int aoff = (wr * 128 + r16) * 128;
  const int boff = (wc * 64 + r16) * 128;
  const int kswz0 = ((hi ^ (r16 & 7)) << 4);
  const int kswz1 = kswz0 ^ 64;

  // ---- prologue: A(0)->slot0, B(0)->par0, A(1)->slot1; wait all but A(1) ----
  STG(xb + m0g * K_DIM,              0);
  STG(xb + (m0g + 128) * K_DIM,      16384);
  STG(wb + n0g * K_DIM,              98304);
  STG(wb + (n0g + 128) * K_DIM,      98304 + 16384);
  STG(xb + m0g * K_DIM + 64,         32768);
  STG(xb + (m0g + 128) * K_DIM + 64, 32768 + 16384);
  asm volatile("s_waitcnt vmcnt(4)");
  __builtin_amdgcn_sched_barrier(0);
  __builtin_amdgcn_s_barrier();

  bf16x8 af_a[2][2], af_b[2][2], bq[4][2];
  f32x4 acc[8][4] = {};

  int sAr = 0, sAn = 32768, sAs = 65536;   // A slots: read(t), read(t+1), stage(t+2)

  for (int t = 0; t < KSTEPS; ++t) {
    const int cur = t & 1;
    const int cB = 98304 + cur * 32768;
    const int nB = 98304 + (cur ^ 1) * 32768;
    const long kB = (long)((t + 1 < KSTEPS ? t + 1 : KSTEPS - 1) * 64);
    const long kA = (long)((t + 2 < KSTEPS ? t + 2 : KSTEPS - 1) * 64);

    // ---- pre: A m0-1, B n0-1 ----
    RD_A2(af_a, 0, sAr);
    RD_B2(0, cB);
    SB;
    // ---- c0 [m01 x n01]; read B n23; stage B(t+1)h0 ----
    RD_B2(2, cB);
    STG(wb + n0g * K_DIM + kB, nB);
    __builtin_amdgcn_s_setprio(1);
    MFP(0, af_a, 0, 0) MFP(1, af_a, 1, 0) MFP(0, af_a, 0, 1) MFP(1, af_a, 1, 1)
    __builtin_amdgcn_s_setprio(0);
    SB;
    // ---- c1 [m01 x n23]; read A m23; stage B(t+1)h1 ----
    RD_A2(af_b, 2, sAr);
    STG(wb + (n0g + 128) * K_DIM + kB, nB + 16384);
    __builtin_amdgcn_s_setprio(1);
    MFP(0, af_a, 0, 2) MFP(1, af_a, 1, 2) MFP(0, af_a, 0, 3) MFP(1, af_a, 1, 3)
    __builtin_amdgcn_s_setprio(0);
    SB;
    // ---- c2 [m23 x n23]; stage A(t+2)h0 ----
    STG(xb + m0g * K_DIM + kA, sAs);
    __builtin_amdgcn_s_setprio(1);
    MFP(2, af_b, 0, 2) MFP(3, af_b, 1, 2) MFP(2, af_b, 0, 3) MFP(3, af_b, 1, 3)
    __builtin_amdgcn_s_setprio(0);
    SB;
    // ---- c3 [m23 x n01]; read A m45; stage A(t+2)h1 ----
    RD_A2(af_a, 4, sAr);
    STG(xb + (m0g + 128) * K_DIM + kA, sAs + 16384);
    __builtin_amdgcn_s_setprio(1);
    MFP(2, af_b, 0, 0) MFP(3, af_b, 1, 0) MFP(2, af_b, 0, 1) MFP(3, af_b, 1, 1)
    __builtin_amdgcn_s_setprio(0);
    SB;
    // ---- c4 [m45 x n01] ----
    __builtin_amdgcn_s_setprio(1);
    MFP(4, af_a, 0, 0) MFP(5, af_a, 1, 0) MFP(4, af_a, 0, 1) MFP(5, af_a, 1, 1)
    __builtin_amdgcn_s_setprio(0);
    SB;
    // ---- c5 [m45 x n23]; read A m67 ----
    RD_A2(af_b, 6, sAr);
    __builtin_amdgcn_s_setprio(1);
    MFP(4, af_a, 0, 2) MFP(5, af_a, 1, 2) MFP(4, af_a, 0, 3) MFP(5, af_a, 1, 3)
    __builtin_amdgcn_s_setprio(0);
    SB;
    // ---- c6 [m67 x n23] ----
    __builtin_amdgcn_s_setprio(1);
    MFP(6, af_b, 0, 2) MFP(7, af_b, 1, 2) MFP(6, af_b, 0, 3) MFP(7, af_b, 1, 3)
    __builtin_amdgcn_s_setprio(0);
    SB;
    // ---- c7 [m67 x n01] ----
    __builtin_amdgcn_s_setprio(1);
    MFP(6, af_b, 0, 0) MFP(7, af_b, 1, 0) MFP(6, af_b, 0, 1) MFP(7, af_b, 1, 1)
    __builtin_amdgcn_s_setprio(0);
    // ---- tile boundary: ONE counted vmcnt + ONE barrier ----
    asm volatile("s_waitcnt vmcnt(4)");   // only A(t+2)'s 4 stages may remain
    __builtin_amdgcn_sched_barrier(0);
    __builtin_amdgcn_s_barrier();
    __builtin_amdgcn_sched_barrier(0);

    int tmp = sAr; sAr = sAn; sAn = sAs; sAs = tmp;   // rotate A slots
  }

  // ---- epilogue: C/D layout col=lane&15, row=hi*4+reg; nontemporal ----
  const long crow = m0g + wr * 128 + hi * 4;
  const long ccol = n0g + wc * 64 + r16;
#pragma unroll
  for (int m = 0; m < 8; ++m)
#pragma unroll
    for (int n = 0; n < 4; ++n)
#pragma unroll
      for (int r = 0; r < 4; ++r)
        __builtin_nontemporal_store(
            acc[m][n][r], &C[(crow + m * 16 + r) * N_DIM + ccol + n * 16]);
}

// ---------------- fallback (no workspace): fused 128^2 kernel ----------------
__global__ __launch_bounds__(256) void gemm_fallback(
    const float* __restrict__ Xf, const int* __restrict__ qw,
    const int* __restrict__ qs, const float* __restrict__ qf,
    const float* __restrict__ meanp, float* __restrict__ C) {
  __shared__ unsigned short As[128 * 64];
  __shared__ unsigned short Bs[128 * 64];
  __shared__ float tbl[16];
  const int tid = threadIdx.x;
  if (tid < 16) tbl[tid] = NF4_TBL[tid];
  const float mu = meanp[0];
  const int nwg = (M_ROWS / 128) * (N_DIM / 128);
  const int wg = ((int)blockIdx.x & 7) * (nwg / 8) + ((int)blockIdx.x >> 3);
  const int mbf = wg % (M_ROWS / 128), nbf = wg / (M_ROWS / 128);
  const int m0 = mbf * 128, n0 = nbf * 128;
  const int wid = tid >> 6, lane = tid & 63;
  const int wrf = wid >> 1, wcc = wid & 1;
  const int r16 = lane & 15, hi = lane >> 4;
  f32x4 acc[4][4] = {};
  for (int t = 0; t < KSTEPS; ++t) {
    const int k0 = t * 64;
    __syncthreads();
#pragma unroll
    for (int i = 0; i < 4; ++i) {
      int gi = i * 256 + tid;
      int row = gi >> 3, kq = (gi & 7) * 8;
      const float* px = Xf + (long)(m0 + row) * K_DIM + k0 + kq;
      f32x4 v0 = *(const f32x4*)px;
      f32x4 v1 = *(const f32x4*)(px + 4);
      u16x8 o;
      o[0] = f2bf(v0[0]); o[1] = f2bf(v0[1]); o[2] = f2bf(v0[2]); o[3] = f2bf(v0[3]);
      o[4] = f2bf(v1[0]); o[5] = f2bf(v1[1]); o[6] = f2bf(v1[2]); o[7] = f2bf(v1[3]);
      *(u16x8*)&As[row * 64 + kq] = o;
    }
#pragma unroll
    for (int i = 0; i < 4; ++i) {
      int gi = i * 256 + tid;
      int row = gi >> 3, kq = (gi & 7) * 8;
      const int* pq = qw + (long)(n0 + row) * K_DIM + k0 + kq;
      i32x4 q0 = *(const i32x4*)pq;
      i32x4 q1 = *(const i32x4*)(pq + 4);
      int g = (n0 + row) * (K_DIM / 64) + t;
      float s = (float)qs[g] / qf[g >> 8] + mu;
      u16x8 o;
      o[0] = f2bf(tbl[q0[0]] * s); o[1] = f2bf(tbl[q0[1]] * s);
      o[2] = f2bf(tbl[q0[2]] * s); o[3] = f2bf(tbl[q0[3]] * s);
      o[4] = f2bf(tbl[q1[0]] * s); o[5] = f2bf(tbl[q1[1]] * s);
      o[6] = f2bf(tbl[q1[2]] * s); o[7] = f2bf(tbl[q1[3]] * s);
      *(u16x8*)&Bs[row * 64 + kq] = o;
    }
    __syncthreads();
    bf16x8 afr[4][2], bfr[4][2];
#pragma unroll
    for (int i = 0; i < 4; ++i)
#pragma unroll
      for (int h = 0; h < 2; ++h) {
        afr[i][h] = *(const bf16x8*)&As[(wrf * 64 + i * 16 + r16) * 64 + h * 32 + hi * 8];
        bfr[i][h] = *(const bf16x8*)&Bs[(wcc * 64 + i * 16 + r16) * 64 + h * 32 + hi * 8];
      }
#pragma unroll
    for (int i = 0; i < 4; ++i)
#pragma unroll
      for (int j = 0; j < 4; ++j) {
        acc[i][j] = __builtin_amdgcn_mfma_f32_16x16x32_bf16(afr[i][0], bfr[j][0], acc[i][j], 0, 0, 0);
        acc[i][j] = __builtin_amdgcn_mfma_f32_16x16x32_bf16(afr[i][1], bfr[j][1], acc[i][j], 0, 0, 0);
      }
  }
  const int crow = m0 + wrf * 64 + hi * 4;
  const int ccol = n0 + wcc * 64 + r16;
#pragma unroll
  for (int i = 0; i < 4; ++i)
#pragma unroll
    for (int j = 0; j < 4; ++j)
#pragma unroll
      for (int r = 0; r < 4; ++r)
        C[(long)(crow + i * 16 + r) * N_DIM + (ccol + j * 16)] = acc[i][j][r];
}

extern "C" void kernel_launch(void* const* d_in, const int* in_sizes, int n_in,
                              void* d_out, int out_size, void* d_ws, size_t ws_size,
                              hipStream_t stream) {
  const float* x    = (const float*)d_in[0];
  const int*   qw   = (const int*)d_in[1];
  const int*   qs   = (const int*)d_in[2];
  const float* qf   = (const float*)d_in[3];
  const float* mean = (const float*)d_in[4];
  float* out = (float*)d_out;

  const size_t xb_bytes = (size_t)M_ROWS * K_DIM * 2;  // 64 MiB
  const size_t wb_bytes = (size_t)N_DIM * K_DIM * 2;   // 86 MiB

  if (ws_size >= xb_bytes + wb_bytes) {
    unsigned short* xb = (unsigned short*)d_ws;
    unsigned short* wb = (unsigned short*)((char*)d_ws + xb_bytes);
    convert_x_kernel<<<4096, 256, 0, stream>>>(x, xb);
    dequant_w_kernel<<<4096, 256, 0, stream>>>(qw, qs, qf, mean, wb);
    gemm_pipe<<<NWG, 512, 0, stream>>>(xb, wb, out);
  } else {
    gemm_fallback<<<(M_ROWS / 128) * (N_DIM / 128), 256, 0, stream>>>(
        x, qw, qs, qf, mean, out);
  }
}

// Round 8
// 689.194 us; speedup vs baseline: 1.2065x; 1.0061x over previous
//
#include <hip/hip_runtime.h>
#include <stdint.h>

#define M_ROWS 8192
#define K_DIM  4096
#define N_DIM  11008
#define KSTEPS (K_DIM / 64)      // 64 K-tiles of BK=64

// ---- 256x256 geometry, 8 waves (2M x 4N), per-wave output 128x64 ----
#define BM 256
#define BN 256
#define MBLKS (M_ROWS / BM)      // 32
#define NBLKS (N_DIM / BN)       // 43
#define NWG   (MBLKS * NBLKS)    // 1376

typedef __attribute__((ext_vector_type(4))) float          f32x4;
typedef __attribute__((ext_vector_type(8))) __bf16         bf16x8;
typedef __attribute__((ext_vector_type(4))) int            i32x4;
typedef __attribute__((ext_vector_type(8))) unsigned short u16x8;

__constant__ float NF4_TBL[16] = {
    -1.0f, -0.6961928009986877f, -0.5250730514526367f, -0.39491748809814453f,
    -0.28444138169288635f, -0.18477343022823334f, -0.10644006729125977f,
    -0.029167551919817924f, 0.0f, 0.07958029955625534f, 0.16093020141124725f,
    0.24611230194568634f, 0.33791524171829224f, 0.44070982933044434f,
    0.5626170039176941f, 0.7229568362236023f};

__device__ __forceinline__ unsigned short f2bf(float f) {
  uint32_t u = __float_as_uint(f);
  u += 0x7fffu + ((u >> 16) & 1u);   // RNE
  return (unsigned short)(u >> 16);
}

__device__ __forceinline__ void gload_lds16(const void* g, const void* l) {
  __builtin_amdgcn_global_load_lds(
      (const __attribute__((address_space(1))) void*)(uintptr_t)g,
      (__attribute__((address_space(3))) void*)(uint32_t)(uintptr_t)l,
      16, 0, 0);
}

// ---------------- prep 1: x fp32 -> bf16 ----------------
__global__ void convert_x_kernel(const float* __restrict__ x,
                                 unsigned short* __restrict__ xb) {
  const long n8 = (long)M_ROWS * K_DIM / 8;
  for (long t = (long)blockIdx.x * blockDim.x + threadIdx.x; t < n8;
       t += (long)gridDim.x * blockDim.x) {
    const float* p = x + t * 8;
    f32x4 v0 = *(const f32x4*)p;
    f32x4 v1 = *(const f32x4*)(p + 4);
    u16x8 o;
    o[0] = f2bf(v0[0]); o[1] = f2bf(v0[1]); o[2] = f2bf(v0[2]); o[3] = f2bf(v0[3]);
    o[4] = f2bf(v1[0]); o[5] = f2bf(v1[1]); o[6] = f2bf(v1[2]); o[7] = f2bf(v1[3]);
    *(u16x8*)(xb + t * 8) = o;
  }
}

// ---------------- prep 2: NF4 dequant W -> bf16 ----------------
__global__ void dequant_w_kernel(const int* __restrict__ qw,
                                 const int* __restrict__ qs,
                                 const float* __restrict__ qf,
                                 const float* __restrict__ mean,
                                 unsigned short* __restrict__ wb) {
  __shared__ float tbl[16];
  if (threadIdx.x < 16) tbl[threadIdx.x] = NF4_TBL[threadIdx.x];
  __syncthreads();
  const float mu = mean[0];
  const long n8 = (long)N_DIM * K_DIM / 8;
  for (long t = (long)blockIdx.x * blockDim.x + threadIdx.x; t < n8;
       t += (long)gridDim.x * blockDim.x) {
    long f = t * 8;
    int  g = (int)(f >> 6);
    float s = (float)qs[g] / qf[g >> 8] + mu;
    i32x4 q0 = *(const i32x4*)(qw + f);
    i32x4 q1 = *(const i32x4*)(qw + f + 4);
    u16x8 o;
    o[0] = f2bf(tbl[q0[0]] * s); o[1] = f2bf(tbl[q0[1]] * s);
    o[2] = f2bf(tbl[q0[2]] * s); o[3] = f2bf(tbl[q0[3]] * s);
    o[4] = f2bf(tbl[q1[0]] * s); o[5] = f2bf(tbl[q1[1]] * s);
    o[6] = f2bf(tbl[q1[2]] * s); o[7] = f2bf(tbl[q1[3]] * s);
    *(u16x8*)(wb + f) = o;
  }
}

// ---------------- 256x256 one-barrier-per-tile bf16 GEMM:  C = A * B^T ----------------
// R7 structure (A triple buffer slot t%3 at 0/32768/65536, B double buffer at
// 98304+par*32768; 8 clusters of 8 MFMA, one-cluster-lookahead ds_reads; ONE
// barrier + ONE counted vmcnt(4) per K-tile; R7 supertile mapping).
// NEW (anti-phase): odd waves run the cluster ring rotated by 4 (start at m45,
// wrap), even waves start at m01. All tile-t operands are resident at tile
// start (staged >=1 tile ahead + barrier), so intra-tile order is free; the
// stage ISSUE sequence (Bh0,Bh1,Ah0,Ah1) is identical in both variants, so the
// per-wave vmcnt(4) ledger and clobber ledger are unchanged; acc updates
// commute. Effect: at any instant ~half the waves use the LDS pipe while the
// other half occupy the MFMA pipe -> pipes overlap instead of alternating.
#define STG(GP, LB)                                                              \
  gload_lds16((GP) + (long)srow * K_DIM + scol, &LDSbuf[(LB) + wid * 1024]);     \
  gload_lds16((GP) + (long)(64 + srow) * K_DIM + scol,                           \
              &LDSbuf[(LB) + 8192 + wid * 1024]);

#define SB __builtin_amdgcn_sched_barrier(0)

#define RD_A2(DST, MB, SA)                                                        \
  DST[0][0] = *(const bf16x8*)&LDSbuf[(SA) + aoff + (MB) * 2048 + kswz0];         \
  DST[0][1] = *(const bf16x8*)&LDSbuf[(SA) + aoff + (MB) * 2048 + kswz1];         \
  DST[1][0] = *(const bf16x8*)&LDSbuf[(SA) + aoff + ((MB) + 1) * 2048 + kswz0];   \
  DST[1][1] = *(const bf16x8*)&LDSbuf[(SA) + aoff + ((MB) + 1) * 2048 + kswz1];

#define RD_B2(NB, CB)                                                             \
  bq[NB][0]     = *(const bf16x8*)&LDSbuf[(CB) + boff + (NB) * 2048 + kswz0];     \
  bq[NB][1]     = *(const bf16x8*)&LDSbuf[(CB) + boff + (NB) * 2048 + kswz1];     \
  bq[NB + 1][0] = *(const bf16x8*)&LDSbuf[(CB) + boff + ((NB) + 1) * 2048 + kswz0];\
  bq[NB + 1][1] = *(const bf16x8*)&LDSbuf[(CB) + boff + ((NB) + 1) * 2048 + kswz1];

#define MFP(MI, AF, AI, NI)                                                       \
  acc[MI][NI] = __builtin_amdgcn_mfma_f32_16x16x32_bf16(AF[AI][0], bq[NI][0], acc[MI][NI], 0, 0, 0); \
  acc[MI][NI] = __builtin_amdgcn_mfma_f32_16x16x32_bf16(AF[AI][1], bq[NI][1], acc[MI][NI], 0, 0, 0);

// full K-tile body, cluster ring rotated by BASE (0 for even waves, 4 for odd)
#define TILE_BODY(BASE)                                                           \
    RD_A2(af_a, ((BASE) + 0) & 7, sAr);                                           \
    RD_B2(0, cB);                                                                 \
    SB;                                                                           \
    RD_B2(2, cB);                                                                 \
    STG(wb + n0g * K_DIM + kB, nB);                                               \
    __builtin_amdgcn_s_setprio(1);                                                \
    MFP(((BASE) + 0) & 7, af_a, 0, 0) MFP(((BASE) + 1) & 7, af_a, 1, 0)           \
    MFP(((BASE) + 0) & 7, af_a, 0, 1) MFP(((BASE) + 1) & 7, af_a, 1, 1)           \
    __builtin_amdgcn_s_setprio(0);                                                \
    SB;                                                                           \
    RD_A2(af_b, ((BASE) + 2) & 7, sAr);                                           \
    STG(wb + (n0g + 128) * K_DIM + kB, nB + 16384);                               \
    __builtin_amdgcn_s_setprio(1);                                                \
    MFP(((BASE) + 0) & 7, af_a, 0, 2) MFP(((BASE) + 1) & 7, af_a, 1, 2)           \
    MFP(((BASE) + 0) & 7, af_a, 0, 3) MFP(((BASE) + 1) & 7, af_a, 1, 3)           \
    __builtin_amdgcn_s_setprio(0);                                                \
    SB;                                                                           \
    STG(xb + m0g * K_DIM + kA, sAs);                                              \
    __builtin_amdgcn_s_setprio(1);                                                \
    MFP(((BASE) + 2) & 7, af_b, 0, 2) MFP(((BASE) + 3) & 7, af_b, 1, 2)           \
    MFP(((BASE) + 2) & 7, af_b, 0, 3) MFP(((BASE) + 3) & 7, af_b, 1, 3)           \
    __builtin_amdgcn_s_setprio(0);                                                \
    SB;                                                                           \
    RD_A2(af_a, ((BASE) + 4) & 7, sAr);                                           \
    STG(xb + (m0g + 128) * K_DIM + kA, sAs + 16384);                              \
    __builtin_amdgcn_s_setprio(1);                                                \
    MFP(((BASE) + 2) & 7, af_b, 0, 0) MFP(((BASE) + 3) & 7, af_b, 1, 0)           \
    MFP(((BASE) + 2) & 7, af_b, 0, 1) MFP(((BASE) + 3) & 7, af_b, 1, 1)           \
    __builtin_amdgcn_s_setprio(0);                                                \
    SB;                                                                           \
    __builtin_amdgcn_s_setprio(1);                                                \
    MFP(((BASE) + 4) & 7, af_a, 0, 0) MFP(((BASE) + 5) & 7, af_a, 1, 0)           \
    MFP(((BASE) + 4) & 7, af_a, 0, 1) MFP(((BASE) + 5) & 7, af_a, 1, 1)           \
    __builtin_amdgcn_s_setprio(0);                                                \
    SB;                                                                           \
    RD_A2(af_b, ((BASE) + 6) & 7, sAr);                                           \
    __builtin_amdgcn_s_setprio(1);                                                \
    MFP(((BASE) + 4) & 7, af_a, 0, 2) MFP(((BASE) + 5) & 7, af_a, 1, 2)           \
    MFP(((BASE) + 4) & 7, af_a, 0, 3) MFP(((BASE) + 5) & 7, af_a, 1, 3)           \
    __builtin_amdgcn_s_setprio(0);                                                \
    SB;                                                                           \
    __builtin_amdgcn_s_setprio(1);                                                \
    MFP(((BASE) + 6) & 7, af_b, 0, 2) MFP(((BASE) + 7) & 7, af_b, 1, 2)           \
    MFP(((BASE) + 6) & 7, af_b, 0, 3) MFP(((BASE) + 7) & 7, af_b, 1, 3)           \
    __builtin_amdgcn_s_setprio(0);                                                \
    SB;                                                                           \
    __builtin_amdgcn_s_setprio(1);                                                \
    MFP(((BASE) + 6) & 7, af_b, 0, 0) MFP(((BASE) + 7) & 7, af_b, 1, 0)           \
    MFP(((BASE) + 6) & 7, af_b, 0, 1) MFP(((BASE) + 7) & 7, af_b, 1, 1)           \
    __builtin_amdgcn_s_setprio(0);

#define TILE_SETUP                                                                \
    const int cur = t & 1;                                                        \
    const int cB = 98304 + cur * 32768;                                           \
    const int nB = 98304 + (cur ^ 1) * 32768;                                     \
    const long kB = (long)((t + 1 < KSTEPS ? t + 1 : KSTEPS - 1) * 64);           \
    const long kA = (long)((t + 2 < KSTEPS ? t + 2 : KSTEPS - 1) * 64);

#define TILE_BOUND                                                                \
    asm volatile("s_waitcnt vmcnt(4)");                                           \
    __builtin_amdgcn_sched_barrier(0);                                            \
    __builtin_amdgcn_s_barrier();                                                 \
    __builtin_amdgcn_sched_barrier(0);                                            \
    int tmp = sAr; sAr = sAn; sAn = sAs; sAs = tmp;

__global__ __launch_bounds__(512, 2) void gemm_pipe(
    const unsigned short* __restrict__ xb, const unsigned short* __restrict__ wb,
    float* __restrict__ C) {
  __align__(16) __shared__ unsigned char LDSbuf[163840];   // 96K A(3) + 64K B(2)

  const int tid = threadIdx.x;
  const int wid = tid >> 6, lane = tid & 63;
  const int wr = wid >> 2, wc = wid & 3;
  const int r16 = lane & 15, hi = lane >> 4;

  // ---- supertile mapping: 8mb x 4nb concurrent per XCD (R7-proven) ----
  const int p = ((int)blockIdx.x & 7) * (NWG / 8) + ((int)blockIdx.x >> 3);
  int mb, nb;
  if (p < 1280) {                 // 10 full nbg x 4 mbg x 32
    const int nbg = p >> 7;
    const int rem = p & 127;
    const int mbg = rem >> 5;
    const int s   = rem & 31;
    mb = mbg * 8 + (s & 7);
    nb = nbg * 4 + (s >> 3);
  } else {                        // ragged tail: nb 40..42, 4 mbg x 24
    const int q   = p - 1280;
    const int mbg = q / 24;
    const int s   = q % 24;
    mb = mbg * 8 + (s & 7);
    nb = 40 + (s >> 3);
  }
  const long m0g = (long)mb * BM, n0g = (long)nb * BN;

  // staging coords (per lane); T2: linear LDS dest, inverse-swizzled source
  const int srow = wid * 8 + (lane >> 3);
  const int scol = ((lane & 7) ^ (lane >> 3)) * 8;

  // ds_read coords (T2 swizzle on read)
  const int aoff = (wr * 128 + r16) * 128;
  const int boff = (wc * 64 + r16) * 128;
  const int kswz0 = ((hi ^ (r16 & 7)) << 4);
  const int kswz1 = kswz0 ^ 64;

  // ---- prologue: A(0)->slot0, B(0)->par0, A(1)->slot1; wait all but A(1) ----
  STG(xb + m0g * K_DIM,              0);
  STG(xb + (m0g + 128) * K_DIM,      16384);
  STG(wb + n0g * K_DIM,              98304);
  STG(wb + (n0g + 128) * K_DIM,      98304 + 16384);
  STG(xb + m0g * K_DIM + 64,         32768);
  STG(xb + (m0g + 128) * K_DIM + 64, 32768 + 16384);
  asm volatile("s_waitcnt vmcnt(4)");
  __builtin_amdgcn_sched_barrier(0);
  __builtin_amdgcn_s_barrier();

  bf16x8 af_a[2][2], af_b[2][2], bq[4][2];
  f32x4 acc[8][4] = {};

  int sAr = 0, sAn = 32768, sAs = 65536;   // A slots: read(t), read(t+1), stage(t+2)

  if ((wid & 1) == 0) {
    for (int t = 0; t < KSTEPS; ++t) {
      TILE_SETUP
      TILE_BODY(0)
      TILE_BOUND
    }
  } else {
    for (int t = 0; t < KSTEPS; ++t) {
      TILE_SETUP
      TILE_BODY(4)
      TILE_BOUND
    }
  }

  // ---- epilogue: C/D layout col=lane&15, row=hi*4+reg; nontemporal ----
  const long crow = m0g + wr * 128 + hi * 4;
  const long ccol = n0g + wc * 64 + r16;
#pragma unroll
  for (int m = 0; m < 8; ++m)
#pragma unroll
    for (int n = 0; n < 4; ++n)
#pragma unroll
      for (int r = 0; r < 4; ++r)
        __builtin_nontemporal_store(
            acc[m][n][r], &C[(crow + m * 16 + r) * N_DIM + ccol + n * 16]);
}

// ---------------- fallback (no workspace): fused 128^2 kernel ----------------
__global__ __launch_bounds__(256) void gemm_fallback(
    const float* __restrict__ Xf, const int* __restrict__ qw,
    const int* __restrict__ qs, const float* __restrict__ qf,
    const float* __restrict__ meanp, float* __restrict__ C) {
  __shared__ unsigned short As[128 * 64];
  __shared__ unsigned short Bs[128 * 64];
  __shared__ float tbl[16];
  const int tid = threadIdx.x;
  if (tid < 16) tbl[tid] = NF4_TBL[tid];
  const float mu = meanp[0];
  const int nwg = (M_ROWS / 128) * (N_DIM / 128);
  const int wg = ((int)blockIdx.x & 7) * (nwg / 8) + ((int)blockIdx.x >> 3);
  const int mbf = wg % (M_ROWS / 128), nbf = wg / (M_ROWS / 128);
  const int m0 = mbf * 128, n0 = nbf * 128;
  const int wid = tid >> 6, lane = tid & 63;
  const int wrf = wid >> 1, wcc = wid & 1;
  const int r16 = lane & 15, hi = lane >> 4;
  f32x4 acc[4][4] = {};
  for (int t = 0; t < KSTEPS; ++t) {
    const int k0 = t * 64;
    __syncthreads();
#pragma unroll
    for (int i = 0; i < 4; ++i) {
      int gi = i * 256 + tid;
      int row = gi >> 3, kq = (gi & 7) * 8;
      const float* px = Xf + (long)(m0 + row) * K_DIM + k0 + kq;
      f32x4 v0 = *(const f32x4*)px;
      f32x4 v1 = *(const f32x4*)(px + 4);
      u16x8 o;
      o[0] = f2bf(v0[0]); o[1] = f2bf(v0[1]); o[2] = f2bf(v0[2]); o[3] = f2bf(v0[3]);
      o[4] = f2bf(v1[0]); o[5] = f2bf(v1[1]); o[6] = f2bf(v1[2]); o[7] = f2bf(v1[3]);
      *(u16x8*)&As[row * 64 + kq] = o;
    }
#pragma unroll
    for (int i = 0; i < 4; ++i) {
      int gi = i * 256 + tid;
      int row = gi >> 3, kq = (gi & 7) * 8;
      const int* pq = qw + (long)(n0 + row) * K_DIM + k0 + kq;
      i32x4 q0 = *(const i32x4*)pq;
      i32x4 q1 = *(const i32x4*)(pq + 4);
      int g = (n0 + row) * (K_DIM / 64) + t;
      float s = (float)qs[g] / qf[g >> 8] + mu;
      u16x8 o;
      o[0] = f2bf(tbl[q0[0]] * s); o[1] = f2bf(tbl[q0[1]] * s);
      o[2] = f2bf(tbl[q0[2]] * s); o[3] = f2bf(tbl[q0[3]] * s);
      o[4] = f2bf(tbl[q1[0]] * s); o[5] = f2bf(tbl[q1[1]] * s);
      o[6] = f2bf(tbl[q1[2]] * s); o[7] = f2bf(tbl[q1[3]] * s);
      *(u16x8*)&Bs[row * 64 + kq] = o;
    }
    __syncthreads();
    bf16x8 afr[4][2], bfr[4][2];
#pragma unroll
    for (int i = 0; i < 4; ++i)
#pragma unroll
      for (int h = 0; h < 2; ++h) {
        afr[i][h] = *(const bf16x8*)&As[(wrf * 64 + i * 16 + r16) * 64 + h * 32 + hi * 8];
        bfr[i][h] = *(const bf16x8*)&Bs[(wcc * 64 + i * 16 + r16) * 64 + h * 32 + hi * 8];
      }
#pragma unroll
    for (int i = 0; i < 4; ++i)
#pragma unroll
      for (int j = 0; j < 4; ++j) {
        acc[i][j] = __builtin_amdgcn_mfma_f32_16x16x32_bf16(afr[i][0], bfr[j][0], acc[i][j], 0, 0, 0);
        acc[i][j] = __builtin_amdgcn_mfma_f32_16x16x32_bf16(afr[i][1], bfr[j][1], acc[i][j], 0, 0, 0);
      }
  }
  const int crow = m0 + wrf * 64 + hi * 4;
  const int ccol = n0 + wcc * 64 + r16;
#pragma unroll
  for (int i = 0; i < 4; ++i)
#pragma unroll
    for (int j = 0; j < 4; ++j)
#pragma unroll
      for (int r = 0; r < 4; ++r)
        C[(long)(crow + i * 16 + r) * N_DIM + (ccol + j * 16)] = acc[i][j][r];
}

extern "C" void kernel_launch(void* const* d_in, const int* in_sizes, int n_in,
                              void* d_out, int out_size, void* d_ws, size_t ws_size,
                              hipStream_t stream) {
  const float* x    = (const float*)d_in[0];
  const int*   qw   = (const int*)d_in[1];
  const int*   qs   = (const int*)d_in[2];
  const float* qf   = (const float*)d_in[3];
  const float* mean = (const float*)d_in[4];
  float* out = (float*)d_out;

  const size_t xb_bytes = (size_t)M_ROWS * K_DIM * 2;  // 64 MiB
  const size_t wb_bytes = (size_t)N_DIM * K_DIM * 2;   // 86 MiB

  if (ws_size >= xb_bytes + wb_bytes) {
    unsigned short* xb = (unsigned short*)d_ws;
    unsigned short* wb = (unsigned short*)((char*)d_ws + xb_bytes);
    convert_x_kernel<<<4096, 256, 0, stream>>>(x, xb);
    dequant_w_kernel<<<4096, 256, 0, stream>>>(qw, qs, qf, mean, wb);
    gemm_pipe<<<NWG, 512, 0, stream>>>(xb, wb, out);
  } else {
    gemm_fallback<<<(M_ROWS / 128) * (N_DIM / 128), 256, 0, stream>>>(
        x, qw, qs, qf, mean, out);
  }
}